// Round 3
// baseline (225.111 us; speedup 1.0000x reference)
//
#include <hip/hip_runtime.h>
#include <hip/hip_bf16.h>

typedef unsigned short u16;
typedef __attribute__((ext_vector_type(8))) short short8;
typedef __attribute__((ext_vector_type(4))) float f32x4;

#define B_SZ 16
#define S_SZ 512
#define D_SZ 1024
#define H_SZ 16
#define DH_SZ 64
#define M_SZ (B_SZ * S_SZ)      // 8192
#define EXPSCALE 0.18033688f    // 0.125 * log2(e)

// direct global->LDS DMA, 16B per lane; LDS dest = wave-uniform base + lane*16
__device__ __forceinline__ void gload_lds16(const void* g, void* l) {
  __builtin_amdgcn_global_load_lds(
      (const __attribute__((address_space(1))) unsigned int*)g,
      (__attribute__((address_space(3))) unsigned int*)l,
      16, 0, 0);
}

// compiler-fenced workgroup barrier: hardware s_barrier + "memory" clobber so
// hipcc cannot hoist LDS reads of other waves' staged data across it.
__device__ __forceinline__ void fenced_barrier() {
  asm volatile("s_barrier" ::: "memory");
}

// ---------------------------------------------------------------------------
// prep: fused f32->bf16 cast of v (blocks 0..8191) + weight transpose+downcast
// ---------------------------------------------------------------------------
__global__ __launch_bounds__(256) void prep(
    const float* __restrict__ v, u16* __restrict__ vB,
    const float* __restrict__ W0, const float* __restrict__ W1,
    const float* __restrict__ W2, const float* __restrict__ W3,
    u16* __restrict__ T0, u16* __restrict__ T1,
    u16* __restrict__ T2, u16* __restrict__ T3) {
  __shared__ float tile[32][33];
  const int bid = blockIdx.x;
  if (bid < 8192) {
    int i = bid * 256 + threadIdx.x;
    const float4 f = *(const float4*)&v[(size_t)i * 4];
    ushort4 o; __hip_bfloat16 h;
    h = __float2bfloat16(f.x); o.x = *(u16*)&h;
    h = __float2bfloat16(f.y); o.y = *(u16*)&h;
    h = __float2bfloat16(f.z); o.z = *(u16*)&h;
    h = __float2bfloat16(f.w); o.w = *(u16*)&h;
    *(ushort4*)&vB[(size_t)i * 4] = o;
    return;
  }
  const int tb = bid - 8192;
  const int z = tb >> 10, rem = tb & 1023;
  const int by = rem >> 5, bx = rem & 31;
  const float* W; u16* T;
  switch (z) {
    case 0: W = W0; T = T0; break;
    case 1: W = W1; T = T1; break;
    case 2: W = W2; T = T2; break;
    default: W = W3; T = T3; break;
  }
  int tx = threadIdx.x & 31, ty = threadIdx.x >> 5;  // 32 x 8
  int x = bx * 32 + tx;
#pragma unroll
  for (int i = 0; i < 32; i += 8)
    tile[ty + i][tx] = W[(size_t)(by * 32 + ty + i) * 1024 + x];
  __syncthreads();
  int x2 = by * 32 + tx;
#pragma unroll
  for (int i = 0; i < 32; i += 8) {
    __hip_bfloat16 h = __float2bfloat16(tile[tx][ty + i]);
    T[(size_t)(bx * 32 + ty + i) * 1024 + x2] = *(u16*)&h;
  }
}

// ---------------------------------------------------------------------------
// GEMM core v2: BM=128 BN=256 BK=64, 8 waves (2M x 4N, 64x64 per wave),
// 3 LDS buffers (144 KiB), prefetch distance 2, counted s_waitcnt vmcnt(6)
// (never drained to 0 in the main loop), raw s_barrier, setprio(1) around
// each 16-MFMA cluster.  16B-granule XOR swizzle (phys = chunk ^ (row&7)) on
// the pre-swizzled global source (linear LDS dest) and on the ds_read addr.
// ---------------------------------------------------------------------------
struct G8 {
  const u16* A; const u16* Bt;
  u16* As; u16* Bs;               // base of As[0], Bs[0]
  int m0, n0;
  int wave, c, quad, r7, wm, wn;
  int srow, slc8;                 // staging geometry
};

#define AS_T (128 * 64)           // elems per A buffer
#define BS_T (256 * 64)           // elems per B buffer

__device__ __forceinline__ void stage_a(const G8& g, int buf, int kt, int i) {
  const int grp = g.wave * 2 + i;                       // 16 groups of 8 rows
  gload_lds16(&g.A[(size_t)(g.m0 + grp * 8 + g.srow) * 1024 + kt * 64 + g.slc8],
              g.As + buf * AS_T + grp * 512);
}
__device__ __forceinline__ void stage_b(const G8& g, int buf, int kt, int i) {
  const int grp = g.wave * 4 + i;                       // 32 groups of 8 rows
  gload_lds16(&g.Bt[(size_t)(g.n0 + grp * 8 + g.srow) * 1024 + kt * 64 + g.slc8],
              g.Bs + buf * BS_T + grp * 512);
}

template<bool ST, int VM>
__device__ __forceinline__ void tile_step(const G8& g, int cur, int stg, int kt2,
                                          f32x4 acc[4][4]) {
  const u16* ab = g.As + cur * AS_T;
  const u16* bb = g.Bs + cur * BS_T;
  short8 af[4], bf[4];

  // ---- phase 0 (kk = 0: k-chunks j = quad) ----
  {
    const int pc = (g.quad ^ g.r7) * 8;
#pragma unroll
    for (int i = 0; i < 4; ++i) {
      af[i] = *(const short8*)&ab[(g.wm + i * 16 + g.c) * 64 + pc];
      bf[i] = *(const short8*)&bb[(g.wn + i * 16 + g.c) * 64 + pc];
    }
    if constexpr (ST) {
      stage_a(g, stg, kt2, 0);
      stage_a(g, stg, kt2, 1);
      stage_b(g, stg, kt2, 0);
    }
    __builtin_amdgcn_s_barrier();
    __builtin_amdgcn_s_setprio(1);
#pragma unroll
    for (int mi = 0; mi < 4; ++mi)
#pragma unroll
      for (int ni = 0; ni < 4; ++ni)
        acc[mi][ni] = __builtin_amdgcn_mfma_f32_16x16x32_bf16(
            af[mi], bf[ni], acc[mi][ni], 0, 0, 0);
    __builtin_amdgcn_s_setprio(0);
    __builtin_amdgcn_s_barrier();
  }

  // ---- phase 1 (kk = 1: k-chunks j = 4+quad) ----
  {
    const int pc = ((4 + g.quad) ^ g.r7) * 8;
#pragma unroll
    for (int i = 0; i < 4; ++i) {
      af[i] = *(const short8*)&ab[(g.wm + i * 16 + g.c) * 64 + pc];
      bf[i] = *(const short8*)&bb[(g.wn + i * 16 + g.c) * 64 + pc];
    }
    if constexpr (ST) {
      stage_b(g, stg, kt2, 1);
      stage_b(g, stg, kt2, 2);
      stage_b(g, stg, kt2, 3);
    }
    __builtin_amdgcn_s_barrier();
    __builtin_amdgcn_s_setprio(1);
#pragma unroll
    for (int mi = 0; mi < 4; ++mi)
#pragma unroll
      for (int ni = 0; ni < 4; ++ni)
        acc[mi][ni] = __builtin_amdgcn_mfma_f32_16x16x32_bf16(
            af[mi], bf[ni], acc[mi][ni], 0, 0, 0);
    __builtin_amdgcn_s_setprio(0);
    if constexpr (VM == 6) {
      asm volatile("s_waitcnt vmcnt(6)" ::: "memory");
      __builtin_amdgcn_s_barrier();
    } else if constexpr (VM == 0) {
      asm volatile("s_waitcnt vmcnt(0)" ::: "memory");
      __builtin_amdgcn_s_barrier();
    }
    // VM == -1: last tile, no wait / no trailing barrier
  }
}

__device__ __forceinline__ void gemm_core8(
    const u16* __restrict__ A, const u16* __restrict__ Bt,
    u16* AsB, u16* BsB, int m0, int n0, f32x4 acc[4][4]) {
  const int tid = threadIdx.x;
  const int lane = tid & 63;
  G8 g;
  g.A = A; g.Bt = Bt; g.As = AsB; g.Bs = BsB;
  g.m0 = m0; g.n0 = n0;
  g.wave = tid >> 6;
  g.c = lane & 15; g.quad = lane >> 4; g.r7 = g.c & 7;
  g.wm = (g.wave >> 2) * 64;          // 2 wave-rows
  g.wn = (g.wave & 3) * 64;           // 4 wave-cols
  g.srow = lane >> 3;                 // 0..7 within 8-row DMA group
  g.slc8 = ((lane & 7) ^ g.srow) * 8; // pre-swizzled source column (elems)

  // prologue: stage K-tiles 0 and 1 (6 loads each, per wave)
  stage_a(g, 0, 0, 0); stage_a(g, 0, 0, 1);
  stage_b(g, 0, 0, 0); stage_b(g, 0, 0, 1); stage_b(g, 0, 0, 2); stage_b(g, 0, 0, 3);
  stage_a(g, 1, 1, 0); stage_a(g, 1, 1, 1);
  stage_b(g, 1, 1, 0); stage_b(g, 1, 1, 1); stage_b(g, 1, 1, 2); stage_b(g, 1, 1, 3);
  asm volatile("s_waitcnt vmcnt(6)" ::: "memory");   // tile 0 resident, tile 1 in flight
  __builtin_amdgcn_s_barrier();

  int cur = 0, stg = 2;
#pragma unroll 1
  for (int t = 0; t < 14; ++t) {      // K/64 = 16 tiles; 14 steady-state iters
    tile_step<true, 6>(g, cur, stg, t + 2, acc);
    cur = (cur == 2) ? 0 : cur + 1;
    stg = (stg == 2) ? 0 : stg + 1;
  }
  tile_step<false, 0>(g, cur, 0, 0, acc);   // tile 14 (cur=2): drain tile 15
  tile_step<false, -1>(g, 0, 0, 0, acc);    // tile 15 (cur=0): final
}

// ---------------------------------------------------------------------------
// Fused QKV GEMM. Grid (64 m, 4 n, 3 z).
// ---------------------------------------------------------------------------
__global__ __launch_bounds__(512, 2) void gemm_qkv(
    const u16* __restrict__ A,
    const u16* __restrict__ BtQ, const u16* __restrict__ BtK, const u16* __restrict__ BtV,
    const float* __restrict__ bq, const float* __restrict__ bk, const float* __restrict__ bv,
    u16* __restrict__ Qo, u16* __restrict__ Kt, u16* __restrict__ Vt) {
  __shared__ u16 As[3][AS_T];
  __shared__ u16 Bs[3][BS_T];
  const int z = blockIdx.z;
  const u16* Bt = (z == 0) ? BtQ : (z == 1) ? BtK : BtV;
  const float* bias = (z == 0) ? bq : (z == 1) ? bk : bv;
  const int m0 = blockIdx.x * 128, n0 = blockIdx.y * 256;

  f32x4 acc[4][4];
#pragma unroll
  for (int i = 0; i < 4; ++i)
#pragma unroll
    for (int j = 0; j < 4; ++j) acc[i][j] = f32x4{0.f, 0.f, 0.f, 0.f};

  gemm_core8(A, Bt, &As[0][0], &Bs[0][0], m0, n0, acc);

  const int lane = threadIdx.x & 63, wave = threadIdx.x >> 6;
  const int wm = (wave >> 2) * 64, wn = (wave & 3) * 64;
  const int c = lane & 15, quad = lane >> 4;
#pragma unroll
  for (int ni = 0; ni < 4; ++ni) {
    int n = n0 + wn + ni * 16 + c;
    float bval = bias[n];
#pragma unroll
    for (int mi = 0; mi < 4; ++mi) {
      int mb = m0 + wm + mi * 16 + quad * 4;
      if (z == 2) {
        int bb = mb >> 9, s = mb & 511, hh = n >> 6, d = n & 63;
        ushort4 st;
        __hip_bfloat16 h0 = __float2bfloat16(acc[mi][ni][0] + bval); st.x = *(u16*)&h0;
        __hip_bfloat16 h1 = __float2bfloat16(acc[mi][ni][1] + bval); st.y = *(u16*)&h1;
        __hip_bfloat16 h2 = __float2bfloat16(acc[mi][ni][2] + bval); st.z = *(u16*)&h2;
        __hip_bfloat16 h3 = __float2bfloat16(acc[mi][ni][3] + bval); st.w = *(u16*)&h3;
        *(ushort4*)&Vt[(((size_t)(bb * 16 + hh) * 64 + d) << 9) + s] = st;
      } else {
#pragma unroll
        for (int r = 0; r < 4; ++r) {
          int m = mb + r;
          float val = acc[mi][ni][r] + bval;
          __hip_bfloat16 hb = __float2bfloat16(val);
          if (z == 0) {
            Qo[(size_t)m * 1024 + n] = *(u16*)&hb;
          } else {
            int bb = m >> 9, s = m & 511, hh = n >> 6, d = n & 63;
            Kt[(((size_t)(bb * 16 + hh) * 512 + s) << 6) + d] = *(u16*)&hb;
          }
        }
      }
    }
  }
}

// ---------------------------------------------------------------------------
// Output GEMM: C_f32 = A @ Bt^T + bias.  Grid (64 m, 4 n) = 256 blocks.
// ---------------------------------------------------------------------------
__global__ __launch_bounds__(512, 2) void gemm_out(
    const u16* __restrict__ A, const u16* __restrict__ Bt,
    const float* __restrict__ bias, float* __restrict__ Cf) {
  __shared__ u16 As[3][AS_T];
  __shared__ u16 Bs[3][BS_T];
  const int m0 = blockIdx.x * 128, n0 = blockIdx.y * 256;

  f32x4 acc[4][4];
#pragma unroll
  for (int i = 0; i < 4; ++i)
#pragma unroll
    for (int j = 0; j < 4; ++j) acc[i][j] = f32x4{0.f, 0.f, 0.f, 0.f};

  gemm_core8(A, Bt, &As[0][0], &Bs[0][0], m0, n0, acc);

  const int lane = threadIdx.x & 63, wave = threadIdx.x >> 6;
  const int wm = (wave >> 2) * 64, wn = (wave & 3) * 64;
  const int c = lane & 15, quad = lane >> 4;
#pragma unroll
  for (int ni = 0; ni < 4; ++ni) {
    int n = n0 + wn + ni * 16 + c;
    float bval = bias[n];
#pragma unroll
    for (int mi = 0; mi < 4; ++mi) {
#pragma unroll
      for (int r = 0; r < 4; ++r) {
        int m = m0 + wm + mi * 16 + quad * 4 + r;
        Cf[(size_t)m * 1024 + n] = acc[mi][ni][r] + bval;
      }
    }
  }
}

// ---------------------------------------------------------------------------
// Attention v7b: double-buffered K/V staging with counted vmcnt, fenced raw
// barriers (asm "s_barrier" + memory clobber).  Per 64-key iter: issue next
// tile's 4 DMAs, s_waitcnt vmcnt(4) (current tile resident, next in flight),
// barrier, compute.  setprio(1) around the PV MFMA cluster.
// Grid (4 qchunks, 16 heads, 16 batches); wave = 32 q rows.  LDS 50 KB.
// ---------------------------------------------------------------------------
__device__ __forceinline__ void attn_stage(
    const u16* __restrict__ Kt, const u16* __restrict__ Vt, size_t hBase,
    int wave, int srow, int slc, int k0, u16* KsB, u16* VsB) {
#pragma unroll
  for (int g = 0; g < 2; ++g) {
    const int rb = (wave * 2 + g) * 8;      // row base (8 rows per DMA)
    gload_lds16(&Kt[hBase + (size_t)(k0 + rb + srow) * 64 + slc * 8],
                &KsB[(wave * 2 + g) * 512]);
    gload_lds16(&Vt[hBase + (size_t)(rb + srow) * 512 + k0 + slc * 8],
                &VsB[(wave * 2 + g) * 512]);
  }
}

__global__ __launch_bounds__(256) void attn_v7(
    const u16* __restrict__ Q, const u16* __restrict__ Kt,
    const u16* __restrict__ Vt, const int* __restrict__ lengths,
    u16* __restrict__ O) {
  const int qc = blockIdx.x, h = blockIdx.y, b = blockIdx.z;
  const int t = threadIdx.x;
  const int lane = t & 63, wave = t >> 6;
  const int c = lane & 15, quad = lane >> 4;
  const int kb = quad * 8;
  const int len = lengths[b];
  const int q0 = qc * 128 + wave * 32;

  __shared__ __align__(16) u16 Ks[2][64 * 64];  // [key][d], swizzled, dbuf
  __shared__ __align__(16) u16 Vs[2][64 * 64];  // [d][s],  swizzled, dbuf
  __shared__ __align__(16) u16 Pt[4][32 * 72];  // per-wave P^T staging

  const size_t bBase = (size_t)b * (S_SZ * D_SZ);
  const size_t hBase = ((size_t)(b * H_SZ + h)) * (S_SZ * DH_SZ);

  short8 aq[2][2];
#pragma unroll
  for (int qt = 0; qt < 2; ++qt) {
    aq[qt][0] = *(const short8*)&Q[bBase + (size_t)(q0 + qt * 16 + c) * 1024 + h * 64 + kb];
    aq[qt][1] = *(const short8*)&Q[bBase + (size_t)(q0 + qt * 16 + c) * 1024 + h * 64 + 32 + kb];
  }

  // staging lane geometry: 8 rows x 8 chunks per 64-lane wave-group
  const int srow = lane >> 3;                 // row within 8-row group
  const int slc = (lane & 7) ^ srow;          // swizzled logical chunk

  float rs[2] = {0.f, 0.f};
  f32x4 o[2][4];
#pragma unroll
  for (int qt = 0; qt < 2; ++qt)
#pragma unroll
    for (int i = 0; i < 4; ++i) o[qt][i] = f32x4{0.f, 0.f, 0.f, 0.f};

  const int kmax = (len + 63) & ~63;
  const int nt = kmax >> 6;

  // prologue: stage tile 0 into buffer 0
  attn_stage(Kt, Vt, hBase, wave, srow, slc, 0, &Ks[0][0], &Vs[0][0]);

#pragma unroll 1
  for (int tt = 0; tt < nt; ++tt) {
    const int k0 = tt << 6;
    if (tt + 1 < nt) {
      attn_stage(Kt, Vt, hBase, wave, srow, slc, k0 + 64,
                 &Ks[(tt + 1) & 1][0], &Vs[(tt + 1) & 1][0]);
      asm volatile("s_waitcnt vmcnt(4)" ::: "memory");  // tile tt resident
    } else {
      asm volatile("s_waitcnt vmcnt(0)" ::: "memory");
    }
    fenced_barrier();   // DMA visible to all waves
    const u16* KsC = &Ks[tt & 1][0];
    const u16* VsC = &Vs[tt & 1][0];

    // --- S^T per 16-key sub-tile: rows = keys, cols = q ---
#pragma unroll
    for (int sub = 0; sub < 4; ++sub) {
      const int row = sub * 16 + c;
      short8 bk0 = *(const short8*)&KsC[row * 64 + ((quad ^ (c & 7))) * 8];
      short8 bk1 = *(const short8*)&KsC[row * 64 + (((4 + quad) ^ (c & 7))) * 8];
      const int keyb = k0 + sub * 16 + quad * 4;
#pragma unroll
      for (int qt = 0; qt < 2; ++qt) {
        f32x4 s = {0.f, 0.f, 0.f, 0.f};
        s = __builtin_amdgcn_mfma_f32_16x16x32_bf16(bk0, aq[qt][0], s, 0, 0, 0);
        s = __builtin_amdgcn_mfma_f32_16x16x32_bf16(bk1, aq[qt][1], s, 0, 0, 0);
        ushort4 st;
        float p0 = (keyb + 0) < len ? exp2f(s[0] * EXPSCALE) : 0.f;
        float p1 = (keyb + 1) < len ? exp2f(s[1] * EXPSCALE) : 0.f;
        float p2 = (keyb + 2) < len ? exp2f(s[2] * EXPSCALE) : 0.f;
        float p3 = (keyb + 3) < len ? exp2f(s[3] * EXPSCALE) : 0.f;
        __hip_bfloat16 h0 = __float2bfloat16(p0); st.x = *(u16*)&h0;
        __hip_bfloat16 h1 = __float2bfloat16(p1); st.y = *(u16*)&h1;
        __hip_bfloat16 h2 = __float2bfloat16(p2); st.z = *(u16*)&h2;
        __hip_bfloat16 h3 = __float2bfloat16(p3); st.w = *(u16*)&h3;
        rs[qt] += __bfloat162float(h0) + __bfloat162float(h1) +
                  __bfloat162float(h2) + __bfloat162float(h3);
        *(ushort4*)&Pt[wave][(qt * 16 + c) * 72 + sub * 16 + quad * 4] = st;
      }
    }
    // --- O += P @ V (V fragments from LDS) ---
    __builtin_amdgcn_s_setprio(1);
#pragma unroll
    for (int ksub = 0; ksub < 2; ++ksub) {
      const short8 pa0 = *(const short8*)&Pt[wave][(c) * 72 + ksub * 32 + kb];
      const short8 pa1 = *(const short8*)&Pt[wave][(16 + c) * 72 + ksub * 32 + kb];
#pragma unroll
      for (int dt = 0; dt < 4; ++dt) {
        const int vrow = dt * 16 + c;
        short8 vb = *(const short8*)&VsC[vrow * 64 + (((ksub * 4 + quad) ^ (c & 7))) * 8];
        o[0][dt] = __builtin_amdgcn_mfma_f32_16x16x32_bf16(pa0, vb, o[0][dt], 0, 0, 0);
        o[1][dt] = __builtin_amdgcn_mfma_f32_16x16x32_bf16(pa1, vb, o[1][dt], 0, 0, 0);
      }
    }
    __builtin_amdgcn_s_setprio(0);
    fenced_barrier();   // all waves done reading buf[tt&1]
  }

  // --- finalize l: reduce across the 4 quads (lanes sharing c) ---
#pragma unroll
  for (int qt = 0; qt < 2; ++qt) {
    rs[qt] += __shfl_xor(rs[qt], 16, 64);
    rs[qt] += __shfl_xor(rs[qt], 32, 64);
  }

#pragma unroll
  for (int qt = 0; qt < 2; ++qt) {
    float lq[4];
#pragma unroll
    for (int r = 0; r < 4; ++r) lq[r] = __shfl(rs[qt], quad * 4 + r, 16);
#pragma unroll
    for (int dt = 0; dt < 4; ++dt) {
#pragma unroll
      for (int r = 0; r < 4; ++r) {
        int s = q0 + qt * 16 + quad * 4 + r;
        float val = o[qt][dt][r] / lq[r];
        __hip_bfloat16 ob = __float2bfloat16(val);
        O[bBase + (size_t)s * 1024 + h * 64 + dt * 16 + c] = *(u16*)&ob;
      }
    }
  }
}

// ---------------------------------------------------------------------------
extern "C" void kernel_launch(void* const* d_in, const int* in_sizes, int n_in,
                              void* d_out, int out_size, void* d_ws, size_t ws_size,
                              hipStream_t stream) {
  const float* v  = (const float*)d_in[0];
  const int* lengths = (const int*)d_in[1];
  const float* Wq = (const float*)d_in[2];
  const float* bq = (const float*)d_in[3];
  const float* Wk = (const float*)d_in[4];
  const float* bk = (const float*)d_in[5];
  const float* Wv = (const float*)d_in[6];
  const float* bv = (const float*)d_in[7];
  const float* Wo = (const float*)d_in[8];
  const float* bo = (const float*)d_in[9];

  char* ws = (char*)d_ws;
  const size_t TSZ = (size_t)M_SZ * D_SZ * 2;   // 16 MiB bf16 activation tensor
  const size_t WSZ = (size_t)1 << 21;           // 2 MiB per transposed weight
  u16* vB  = (u16*)(ws);                        // aliased: AO reuses this after QKV
  u16* AO  = vB;
  u16* WqT = (u16*)(ws + TSZ + 0 * WSZ);
  u16* WkT = (u16*)(ws + TSZ + 1 * WSZ);
  u16* WvT = (u16*)(ws + TSZ + 2 * WSZ);
  u16* WoT = (u16*)(ws + TSZ + 3 * WSZ);
  u16* Qb  = (u16*)(ws + TSZ + 4 * WSZ + 0 * TSZ);
  u16* Kt  = (u16*)(ws + TSZ + 4 * WSZ + 1 * TSZ);
  u16* Vt  = (u16*)(ws + TSZ + 4 * WSZ + 2 * TSZ);

  prep<<<dim3(8192 + 4096), 256, 0, stream>>>(v, vB, Wq, Wk, Wv, Wo, WqT, WkT, WvT, WoT);

  gemm_qkv<<<dim3(64, 4, 3), 512, 0, stream>>>(vB, WqT, WkT, WvT, bq, bk, bv, Qb, Kt, Vt);

  attn_v7<<<dim3(4, 16, 16), 256, 0, stream>>>(Qb, Kt, Vt, lengths, AO);

  gemm_out<<<dim3(64, 4), 512, 0, stream>>>(AO, WoT, bo, (float*)d_out);
}

// Round 4
// 224.654 us; speedup vs baseline: 1.0020x; 1.0020x over previous
//
#include <hip/hip_runtime.h>
#include <hip/hip_bf16.h>

typedef unsigned short u16;
typedef __attribute__((ext_vector_type(8))) short short8;
typedef __attribute__((ext_vector_type(4))) float f32x4;

#define B_SZ 16
#define S_SZ 512
#define D_SZ 1024
#define H_SZ 16
#define DH_SZ 64
#define M_SZ (B_SZ * S_SZ)      // 8192
#define EXPSCALE 0.18033688f    // 0.125 * log2(e)

// direct global->LDS DMA, 16B per lane; LDS dest = wave-uniform base + lane*16
__device__ __forceinline__ void gload_lds16(const void* g, void* l) {
  __builtin_amdgcn_global_load_lds(
      (const __attribute__((address_space(1))) unsigned int*)g,
      (__attribute__((address_space(3))) unsigned int*)l,
      16, 0, 0);
}

// ---------------------------------------------------------------------------
// prep: fused f32->bf16 cast of v (blocks 0..8191) + weight transpose+downcast
// ---------------------------------------------------------------------------
__global__ __launch_bounds__(256) void prep(
    const float* __restrict__ v, u16* __restrict__ vB,
    const float* __restrict__ W0, const float* __restrict__ W1,
    const float* __restrict__ W2, const float* __restrict__ W3,
    u16* __restrict__ T0, u16* __restrict__ T1,
    u16* __restrict__ T2, u16* __restrict__ T3) {
  __shared__ float tile[32][33];
  const int bid = blockIdx.x;
  if (bid < 8192) {
    int i = bid * 256 + threadIdx.x;
    const float4 f = *(const float4*)&v[(size_t)i * 4];
    ushort4 o; __hip_bfloat16 h;
    h = __float2bfloat16(f.x); o.x = *(u16*)&h;
    h = __float2bfloat16(f.y); o.y = *(u16*)&h;
    h = __float2bfloat16(f.z); o.z = *(u16*)&h;
    h = __float2bfloat16(f.w); o.w = *(u16*)&h;
    *(ushort4*)&vB[(size_t)i * 4] = o;
    return;
  }
  const int tb = bid - 8192;
  const int z = tb >> 10, rem = tb & 1023;
  const int by = rem >> 5, bx = rem & 31;
  const float* W; u16* T;
  switch (z) {
    case 0: W = W0; T = T0; break;
    case 1: W = W1; T = T1; break;
    case 2: W = W2; T = T2; break;
    default: W = W3; T = T3; break;
  }
  int tx = threadIdx.x & 31, ty = threadIdx.x >> 5;  // 32 x 8
  int x = bx * 32 + tx;
#pragma unroll
  for (int i = 0; i < 32; i += 8)
    tile[ty + i][tx] = W[(size_t)(by * 32 + ty + i) * 1024 + x];
  __syncthreads();
  int x2 = by * 32 + tx;
#pragma unroll
  for (int i = 0; i < 32; i += 8) {
    __hip_bfloat16 h = __float2bfloat16(tile[tx][ty + i]);
    T[(size_t)(bx * 32 + ty + i) * 1024 + x2] = *(u16*)&h;
  }
}

// ---------------------------------------------------------------------------
// GEMM core: BM=128 BN=256 BK=64, 8 waves (2M x 4N, 64x64 per wave),
// 3 LDS buffers (144 KiB), prefetch distance 2, counted s_waitcnt vmcnt(6)
// (never drained to 0 in the main loop), raw s_barrier, setprio(1) around
// each 16-MFMA cluster.  16B-granule XOR swizzle (phys = chunk ^ (row&7)) on
// the pre-swizzled global source (linear LDS dest) and on the ds_read addr.
// ---------------------------------------------------------------------------
struct G8 {
  const u16* A; const u16* Bt;
  u16* As; u16* Bs;               // base of As[0], Bs[0]
  int m0, n0;
  int wave, c, quad, r7, wm, wn;
  int srow, slc8;                 // staging geometry
};

#define AS_T (128 * 64)           // elems per A buffer
#define BS_T (256 * 64)           // elems per B buffer

__device__ __forceinline__ void stage_a(const G8& g, int buf, int kt, int i) {
  const int grp = g.wave * 2 + i;                       // 16 groups of 8 rows
  gload_lds16(&g.A[(size_t)(g.m0 + grp * 8 + g.srow) * 1024 + kt * 64 + g.slc8],
              g.As + buf * AS_T + grp * 512);
}
__device__ __forceinline__ void stage_b(const G8& g, int buf, int kt, int i) {
  const int grp = g.wave * 4 + i;                       // 32 groups of 8 rows
  gload_lds16(&g.Bt[(size_t)(g.n0 + grp * 8 + g.srow) * 1024 + kt * 64 + g.slc8],
              g.Bs + buf * BS_T + grp * 512);
}

template<bool ST, int VM>
__device__ __forceinline__ void tile_step(const G8& g, int cur, int stg, int kt2,
                                          f32x4 acc[4][4]) {
  const u16* ab = g.As + cur * AS_T;
  const u16* bb = g.Bs + cur * BS_T;
  short8 af[4], bf[4];

  // ---- phase 0 (kk = 0: k-chunks j = quad) ----
  {
    const int pc = (g.quad ^ g.r7) * 8;
#pragma unroll
    for (int i = 0; i < 4; ++i) {
      af[i] = *(const short8*)&ab[(g.wm + i * 16 + g.c) * 64 + pc];
      bf[i] = *(const short8*)&bb[(g.wn + i * 16 + g.c) * 64 + pc];
    }
    if constexpr (ST) {
      stage_a(g, stg, kt2, 0);
      stage_a(g, stg, kt2, 1);
      stage_b(g, stg, kt2, 0);
    }
    __builtin_amdgcn_s_barrier();
    __builtin_amdgcn_s_setprio(1);
#pragma unroll
    for (int mi = 0; mi < 4; ++mi)
#pragma unroll
      for (int ni = 0; ni < 4; ++ni)
        acc[mi][ni] = __builtin_amdgcn_mfma_f32_16x16x32_bf16(
            af[mi], bf[ni], acc[mi][ni], 0, 0, 0);
    __builtin_amdgcn_s_setprio(0);
    __builtin_amdgcn_s_barrier();
  }

  // ---- phase 1 (kk = 1: k-chunks j = 4+quad) ----
  {
    const int pc = ((4 + g.quad) ^ g.r7) * 8;
#pragma unroll
    for (int i = 0; i < 4; ++i) {
      af[i] = *(const short8*)&ab[(g.wm + i * 16 + g.c) * 64 + pc];
      bf[i] = *(const short8*)&bb[(g.wn + i * 16 + g.c) * 64 + pc];
    }
    if constexpr (ST) {
      stage_b(g, stg, kt2, 1);
      stage_b(g, stg, kt2, 2);
      stage_b(g, stg, kt2, 3);
    }
    __builtin_amdgcn_s_barrier();
    __builtin_amdgcn_s_setprio(1);
#pragma unroll
    for (int mi = 0; mi < 4; ++mi)
#pragma unroll
      for (int ni = 0; ni < 4; ++ni)
        acc[mi][ni] = __builtin_amdgcn_mfma_f32_16x16x32_bf16(
            af[mi], bf[ni], acc[mi][ni], 0, 0, 0);
    __builtin_amdgcn_s_setprio(0);
    if constexpr (VM == 6) {
      asm volatile("s_waitcnt vmcnt(6)" ::: "memory");
      __builtin_amdgcn_s_barrier();
    } else if constexpr (VM == 0) {
      asm volatile("s_waitcnt vmcnt(0)" ::: "memory");
      __builtin_amdgcn_s_barrier();
    }
    // VM == -1: last tile, no wait / no trailing barrier
  }
}

__device__ __forceinline__ void gemm_core8(
    const u16* __restrict__ A, const u16* __restrict__ Bt,
    u16* AsB, u16* BsB, int m0, int n0, f32x4 acc[4][4]) {
  const int tid = threadIdx.x;
  const int lane = tid & 63;
  G8 g;
  g.A = A; g.Bt = Bt; g.As = AsB; g.Bs = BsB;
  g.m0 = m0; g.n0 = n0;
  g.wave = tid >> 6;
  g.c = lane & 15; g.quad = lane >> 4; g.r7 = g.c & 7;
  g.wm = (g.wave >> 2) * 64;          // 2 wave-rows
  g.wn = (g.wave & 3) * 64;           // 4 wave-cols
  g.srow = lane >> 3;                 // 0..7 within 8-row DMA group
  g.slc8 = ((lane & 7) ^ g.srow) * 8; // pre-swizzled source column (elems)

  // prologue: stage K-tiles 0 and 1 (6 loads each, per wave)
  stage_a(g, 0, 0, 0); stage_a(g, 0, 0, 1);
  stage_b(g, 0, 0, 0); stage_b(g, 0, 0, 1); stage_b(g, 0, 0, 2); stage_b(g, 0, 0, 3);
  stage_a(g, 1, 1, 0); stage_a(g, 1, 1, 1);
  stage_b(g, 1, 1, 0); stage_b(g, 1, 1, 1); stage_b(g, 1, 1, 2); stage_b(g, 1, 1, 3);
  asm volatile("s_waitcnt vmcnt(6)" ::: "memory");   // tile 0 resident, tile 1 in flight
  __builtin_amdgcn_s_barrier();

  int cur = 0, stg = 2;
#pragma unroll 1
  for (int t = 0; t < 14; ++t) {      // K/64 = 16 tiles; 14 steady-state iters
    tile_step<true, 6>(g, cur, stg, t + 2, acc);
    cur = (cur == 2) ? 0 : cur + 1;
    stg = (stg == 2) ? 0 : stg + 1;
  }
  tile_step<false, 0>(g, cur, 0, 0, acc);   // tile 14 (cur=2): drain tile 15
  tile_step<false, -1>(g, 0, 0, 0, acc);    // tile 15 (cur=0): final
}

// ---------------------------------------------------------------------------
// Split QKV GEMM: one GEMM per launch so rocprof top-5 surfaces the other
// kernels (attn/prep/gemm_out) with counters.  Grid (64 m, 4 n) = 256 blocks
// = exactly 1 block/CU.  Z=0: Q (row-major), Z=1: K ([b,h,s,d]), Z=2: V
// ([b,h,d,s]).
// ---------------------------------------------------------------------------
template<int Z>
__global__ __launch_bounds__(512, 2) void gemm_split(
    const u16* __restrict__ A, const u16* __restrict__ Bt,
    const float* __restrict__ bias, u16* __restrict__ Out) {
  __shared__ u16 As[3][AS_T];
  __shared__ u16 Bs[3][BS_T];
  const int m0 = blockIdx.x * 128, n0 = blockIdx.y * 256;

  f32x4 acc[4][4];
#pragma unroll
  for (int i = 0; i < 4; ++i)
#pragma unroll
    for (int j = 0; j < 4; ++j) acc[i][j] = f32x4{0.f, 0.f, 0.f, 0.f};

  gemm_core8(A, Bt, &As[0][0], &Bs[0][0], m0, n0, acc);

  const int lane = threadIdx.x & 63, wave = threadIdx.x >> 6;
  const int wm = (wave >> 2) * 64, wn = (wave & 3) * 64;
  const int c = lane & 15, quad = lane >> 4;
#pragma unroll
  for (int ni = 0; ni < 4; ++ni) {
    int n = n0 + wn + ni * 16 + c;
    float bval = bias[n];
#pragma unroll
    for (int mi = 0; mi < 4; ++mi) {
      int mb = m0 + wm + mi * 16 + quad * 4;
      if constexpr (Z == 2) {
        int bb = mb >> 9, s = mb & 511, hh = n >> 6, d = n & 63;
        ushort4 st;
        __hip_bfloat16 h0 = __float2bfloat16(acc[mi][ni][0] + bval); st.x = *(u16*)&h0;
        __hip_bfloat16 h1 = __float2bfloat16(acc[mi][ni][1] + bval); st.y = *(u16*)&h1;
        __hip_bfloat16 h2 = __float2bfloat16(acc[mi][ni][2] + bval); st.z = *(u16*)&h2;
        __hip_bfloat16 h3 = __float2bfloat16(acc[mi][ni][3] + bval); st.w = *(u16*)&h3;
        *(ushort4*)&Out[(((size_t)(bb * 16 + hh) * 64 + d) << 9) + s] = st;
      } else {
#pragma unroll
        for (int r = 0; r < 4; ++r) {
          int m = mb + r;
          float val = acc[mi][ni][r] + bval;
          __hip_bfloat16 hb = __float2bfloat16(val);
          if constexpr (Z == 0) {
            Out[(size_t)m * 1024 + n] = *(u16*)&hb;
          } else {
            int bb = m >> 9, s = m & 511, hh = n >> 6, d = n & 63;
            Out[(((size_t)(bb * 16 + hh) * 512 + s) << 6) + d] = *(u16*)&hb;
          }
        }
      }
    }
  }
}

// ---------------------------------------------------------------------------
// Output GEMM: C_f32 = A @ Bt^T + bias.  Grid (64 m, 4 n) = 256 blocks.
// ---------------------------------------------------------------------------
__global__ __launch_bounds__(512, 2) void gemm_out(
    const u16* __restrict__ A, const u16* __restrict__ Bt,
    const float* __restrict__ bias, float* __restrict__ Cf) {
  __shared__ u16 As[3][AS_T];
  __shared__ u16 Bs[3][BS_T];
  const int m0 = blockIdx.x * 128, n0 = blockIdx.y * 256;

  f32x4 acc[4][4];
#pragma unroll
  for (int i = 0; i < 4; ++i)
#pragma unroll
    for (int j = 0; j < 4; ++j) acc[i][j] = f32x4{0.f, 0.f, 0.f, 0.f};

  gemm_core8(A, Bt, &As[0][0], &Bs[0][0], m0, n0, acc);

  const int lane = threadIdx.x & 63, wave = threadIdx.x >> 6;
  const int wm = (wave >> 2) * 64, wn = (wave & 3) * 64;
  const int c = lane & 15, quad = lane >> 4;
#pragma unroll
  for (int ni = 0; ni < 4; ++ni) {
    int n = n0 + wn + ni * 16 + c;
    float bval = bias[n];
#pragma unroll
    for (int mi = 0; mi < 4; ++mi) {
#pragma unroll
      for (int r = 0; r < 4; ++r) {
        int m = m0 + wm + mi * 16 + quad * 4 + r;
        Cf[(size_t)m * 1024 + n] = acc[mi][ni][r] + bval;
      }
    }
  }
}

// ---------------------------------------------------------------------------
// Attention v6 (round-1 best-known): S^T MFMA, no-max softmax, cooperative
// K/V LDS staging with __syncthreads.  Grid (4 qchunks, 16 heads, 16 batches).
// ---------------------------------------------------------------------------
__global__ __launch_bounds__(256) void attn_v6(
    const u16* __restrict__ Q, const u16* __restrict__ Kt,
    const u16* __restrict__ Vt, const int* __restrict__ lengths,
    u16* __restrict__ O) {
  const int qc = blockIdx.x, h = blockIdx.y, b = blockIdx.z;
  const int t = threadIdx.x;
  const int lane = t & 63, wave = t >> 6;
  const int c = lane & 15, quad = lane >> 4;
  const int kb = quad * 8;
  const int len = lengths[b];
  const int q0 = qc * 128 + wave * 32;

  __shared__ __align__(16) u16 Ks[64 * 64];     // [key][d], swizzled
  __shared__ __align__(16) u16 Vs[64 * 64];     // [d][s],  swizzled
  __shared__ __align__(16) u16 Pt[4][32 * 72];  // per-wave P^T staging

  const size_t bBase = (size_t)b * (S_SZ * D_SZ);
  const size_t hBase = ((size_t)(b * H_SZ + h)) * (S_SZ * DH_SZ);

  short8 aq[2][2];
#pragma unroll
  for (int qt = 0; qt < 2; ++qt) {
    aq[qt][0] = *(const short8*)&Q[bBase + (size_t)(q0 + qt * 16 + c) * 1024 + h * 64 + kb];
    aq[qt][1] = *(const short8*)&Q[bBase + (size_t)(q0 + qt * 16 + c) * 1024 + h * 64 + 32 + kb];
  }

  // staging lane geometry: 8 rows x 8 chunks per 64-lane wave-group
  const int srow = lane >> 3;                 // row within 8-row group
  const int slc = (lane & 7) ^ srow;          // swizzled logical chunk

  float rs[2] = {0.f, 0.f};
  f32x4 o[2][4];
#pragma unroll
  for (int qt = 0; qt < 2; ++qt)
#pragma unroll
    for (int i = 0; i < 4; ++i) o[qt][i] = f32x4{0.f, 0.f, 0.f, 0.f};

  const int kmax = (len + 63) & ~63;
  for (int k0 = 0; k0 < kmax; k0 += 64) {
    __syncthreads();   // previous iter's LDS reads complete
#pragma unroll
    for (int g = 0; g < 2; ++g) {
      const int rb = (wave * 2 + g) * 8;      // row base (8 rows per DMA)
      gload_lds16(&Kt[hBase + (size_t)(k0 + rb + srow) * 64 + slc * 8],
                  &Ks[(wave * 2 + g) * 512]);
      gload_lds16(&Vt[hBase + (size_t)(rb + srow) * 512 + k0 + slc * 8],
                  &Vs[(wave * 2 + g) * 512]);
    }
    __syncthreads();   // DMA visible to all waves

    // --- S^T per 16-key sub-tile: rows = keys, cols = q ---
#pragma unroll
    for (int sub = 0; sub < 4; ++sub) {
      const int row = sub * 16 + c;
      short8 bk0 = *(const short8*)&Ks[row * 64 + ((quad ^ (c & 7))) * 8];
      short8 bk1 = *(const short8*)&Ks[row * 64 + (((4 + quad) ^ (c & 7))) * 8];
      const int keyb = k0 + sub * 16 + quad * 4;
#pragma unroll
      for (int qt = 0; qt < 2; ++qt) {
        f32x4 s = {0.f, 0.f, 0.f, 0.f};
        s = __builtin_amdgcn_mfma_f32_16x16x32_bf16(bk0, aq[qt][0], s, 0, 0, 0);
        s = __builtin_amdgcn_mfma_f32_16x16x32_bf16(bk1, aq[qt][1], s, 0, 0, 0);
        ushort4 st;
        float p0 = (keyb + 0) < len ? exp2f(s[0] * EXPSCALE) : 0.f;
        float p1 = (keyb + 1) < len ? exp2f(s[1] * EXPSCALE) : 0.f;
        float p2 = (keyb + 2) < len ? exp2f(s[2] * EXPSCALE) : 0.f;
        float p3 = (keyb + 3) < len ? exp2f(s[3] * EXPSCALE) : 0.f;
        __hip_bfloat16 h0 = __float2bfloat16(p0); st.x = *(u16*)&h0;
        __hip_bfloat16 h1 = __float2bfloat16(p1); st.y = *(u16*)&h1;
        __hip_bfloat16 h2 = __float2bfloat16(p2); st.z = *(u16*)&h2;
        __hip_bfloat16 h3 = __float2bfloat16(p3); st.w = *(u16*)&h3;
        rs[qt] += __bfloat162float(h0) + __bfloat162float(h1) +
                  __bfloat162float(h2) + __bfloat162float(h3);
        *(ushort4*)&Pt[wave][(qt * 16 + c) * 72 + sub * 16 + quad * 4] = st;
      }
    }
    // --- O += P @ V (V fragments from LDS) ---
#pragma unroll
    for (int ksub = 0; ksub < 2; ++ksub) {
      const short8 pa0 = *(const short8*)&Pt[wave][(c) * 72 + ksub * 32 + kb];
      const short8 pa1 = *(const short8*)&Pt[wave][(16 + c) * 72 + ksub * 32 + kb];
#pragma unroll
      for (int dt = 0; dt < 4; ++dt) {
        const int vrow = dt * 16 + c;
        short8 vb = *(const short8*)&Vs[vrow * 64 + (((ksub * 4 + quad) ^ (c & 7))) * 8];
        o[0][dt] = __builtin_amdgcn_mfma_f32_16x16x32_bf16(pa0, vb, o[0][dt], 0, 0, 0);
        o[1][dt] = __builtin_amdgcn_mfma_f32_16x16x32_bf16(pa1, vb, o[1][dt], 0, 0, 0);
      }
    }
  }

  // --- finalize l: reduce across the 4 quads (lanes sharing c) ---
#pragma unroll
  for (int qt = 0; qt < 2; ++qt) {
    rs[qt] += __shfl_xor(rs[qt], 16, 64);
    rs[qt] += __shfl_xor(rs[qt], 32, 64);
  }

#pragma unroll
  for (int qt = 0; qt < 2; ++qt) {
    float lq[4];
#pragma unroll
    for (int r = 0; r < 4; ++r) lq[r] = __shfl(rs[qt], quad * 4 + r, 16);
#pragma unroll
    for (int dt = 0; dt < 4; ++dt) {
#pragma unroll
      for (int r = 0; r < 4; ++r) {
        int s = q0 + qt * 16 + quad * 4 + r;
        float val = o[qt][dt][r] / lq[r];
        __hip_bfloat16 ob = __float2bfloat16(val);
        O[bBase + (size_t)s * 1024 + h * 64 + dt * 16 + c] = *(u16*)&ob;
      }
    }
  }
}

// ---------------------------------------------------------------------------
extern "C" void kernel_launch(void* const* d_in, const int* in_sizes, int n_in,
                              void* d_out, int out_size, void* d_ws, size_t ws_size,
                              hipStream_t stream) {
  const float* v  = (const float*)d_in[0];
  const int* lengths = (const int*)d_in[1];
  const float* Wq = (const float*)d_in[2];
  const float* bq = (const float*)d_in[3];
  const float* Wk = (const float*)d_in[4];
  const float* bk = (const float*)d_in[5];
  const float* Wv = (const float*)d_in[6];
  const float* bv = (const float*)d_in[7];
  const float* Wo = (const float*)d_in[8];
  const float* bo = (const float*)d_in[9];

  char* ws = (char*)d_ws;
  const size_t TSZ = (size_t)M_SZ * D_SZ * 2;   // 16 MiB bf16 activation tensor
  const size_t WSZ = (size_t)1 << 21;           // 2 MiB per transposed weight
  u16* vB  = (u16*)(ws);                        // aliased: AO reuses this after QKV
  u16* AO  = vB;
  u16* WqT = (u16*)(ws + TSZ + 0 * WSZ);
  u16* WkT = (u16*)(ws + TSZ + 1 * WSZ);
  u16* WvT = (u16*)(ws + TSZ + 2 * WSZ);
  u16* WoT = (u16*)(ws + TSZ + 3 * WSZ);
  u16* Qb  = (u16*)(ws + TSZ + 4 * WSZ + 0 * TSZ);
  u16* Kt  = (u16*)(ws + TSZ + 4 * WSZ + 1 * TSZ);
  u16* Vt  = (u16*)(ws + TSZ + 4 * WSZ + 2 * TSZ);

  prep<<<dim3(8192 + 4096), 256, 0, stream>>>(v, vB, Wq, Wk, Wv, Wo, WqT, WkT, WvT, WoT);

  gemm_split<0><<<dim3(64, 4), 512, 0, stream>>>(vB, WqT, bq, Qb);
  gemm_split<1><<<dim3(64, 4), 512, 0, stream>>>(vB, WkT, bk, Kt);
  gemm_split<2><<<dim3(64, 4), 512, 0, stream>>>(vB, WvT, bv, Vt);

  attn_v6<<<dim3(4, 16, 16), 256, 0, stream>>>(Qb, Kt, Vt, lengths, AO);

  gemm_out<<<dim3(64, 4), 512, 0, stream>>>(AO, WoT, bo, (float*)d_out);
}

// Round 5
// 219.732 us; speedup vs baseline: 1.0245x; 1.0224x over previous
//
#include <hip/hip_runtime.h>
#include <hip/hip_bf16.h>

typedef unsigned short u16;
typedef __attribute__((ext_vector_type(8))) short short8;
typedef __attribute__((ext_vector_type(4))) float f32x4;

#define B_SZ 16
#define S_SZ 512
#define D_SZ 1024
#define H_SZ 16
#define DH_SZ 64
#define M_SZ (B_SZ * S_SZ)      // 8192
#define EXPSCALE 0.18033688f    // 0.125 * log2(e)

// direct global->LDS DMA, 16B per lane; LDS dest = wave-uniform base + lane*16
__device__ __forceinline__ void gload_lds16(const void* g, void* l) {
  __builtin_amdgcn_global_load_lds(
      (const __attribute__((address_space(1))) unsigned int*)g,
      (__attribute__((address_space(3))) unsigned int*)l,
      16, 0, 0);
}

// ---------------------------------------------------------------------------
// prep: fused f32->bf16 cast of v (blocks 0..8191) + weight transpose+downcast
// ---------------------------------------------------------------------------
__global__ __launch_bounds__(256) void prep(
    const float* __restrict__ v, u16* __restrict__ vB,
    const float* __restrict__ W0, const float* __restrict__ W1,
    const float* __restrict__ W2, const float* __restrict__ W3,
    u16* __restrict__ T0, u16* __restrict__ T1,
    u16* __restrict__ T2, u16* __restrict__ T3) {
  __shared__ float tile[32][33];
  const int bid = blockIdx.x;
  if (bid < 8192) {
    int i = bid * 256 + threadIdx.x;
    const float4 f = *(const float4*)&v[(size_t)i * 4];
    ushort4 o; __hip_bfloat16 h;
    h = __float2bfloat16(f.x); o.x = *(u16*)&h;
    h = __float2bfloat16(f.y); o.y = *(u16*)&h;
    h = __float2bfloat16(f.z); o.z = *(u16*)&h;
    h = __float2bfloat16(f.w); o.w = *(u16*)&h;
    *(ushort4*)&vB[(size_t)i * 4] = o;
    return;
  }
  const int tb = bid - 8192;
  const int z = tb >> 10, rem = tb & 1023;
  const int by = rem >> 5, bx = rem & 31;
  const float* W; u16* T;
  switch (z) {
    case 0: W = W0; T = T0; break;
    case 1: W = W1; T = T1; break;
    case 2: W = W2; T = T2; break;
    default: W = W3; T = T3; break;
  }
  int tx = threadIdx.x & 31, ty = threadIdx.x >> 5;  // 32 x 8
  int x = bx * 32 + tx;
#pragma unroll
  for (int i = 0; i < 32; i += 8)
    tile[ty + i][tx] = W[(size_t)(by * 32 + ty + i) * 1024 + x];
  __syncthreads();
  int x2 = by * 32 + tx;
#pragma unroll
  for (int i = 0; i < 32; i += 8) {
    __hip_bfloat16 h = __float2bfloat16(tile[tx][ty + i]);
    T[(size_t)(bx * 32 + ty + i) * 1024 + x2] = *(u16*)&h;
  }
}

// ---------------------------------------------------------------------------
// GEMM core: BM=128 BN=256 BK=64, 8 waves (2M x 4N, 64x64 per wave),
// 3 LDS buffers (144 KiB), prefetch distance 2, counted s_waitcnt vmcnt(6)
// (never drained to 0 in the main loop), raw s_barrier, setprio(1) around
// each 16-MFMA cluster.  16B-granule XOR swizzle (phys = chunk ^ (row&7)) on
// the pre-swizzled global source (linear LDS dest) and on the ds_read addr.
// ---------------------------------------------------------------------------
struct G8 {
  const u16* A; const u16* Bt;
  u16* As; u16* Bs;               // base of As[0], Bs[0]
  int m0, n0;
  int wave, c, quad, r7, wm, wn;
  int srow, slc8;                 // staging geometry
};

#define AS_T (128 * 64)           // elems per A buffer
#define BS_T (256 * 64)           // elems per B buffer

__device__ __forceinline__ void stage_a(const G8& g, int buf, int kt, int i) {
  const int grp = g.wave * 2 + i;                       // 16 groups of 8 rows
  gload_lds16(&g.A[(size_t)(g.m0 + grp * 8 + g.srow) * 1024 + kt * 64 + g.slc8],
              g.As + buf * AS_T + grp * 512);
}
__device__ __forceinline__ void stage_b(const G8& g, int buf, int kt, int i) {
  const int grp = g.wave * 4 + i;                       // 32 groups of 8 rows
  gload_lds16(&g.Bt[(size_t)(g.n0 + grp * 8 + g.srow) * 1024 + kt * 64 + g.slc8],
              g.Bs + buf * BS_T + grp * 512);
}

template<bool ST, int VM>
__device__ __forceinline__ void tile_step(const G8& g, int cur, int stg, int kt2,
                                          f32x4 acc[4][4]) {
  const u16* ab = g.As + cur * AS_T;
  const u16* bb = g.Bs + cur * BS_T;
  short8 af[4], bf[4];

  // ---- phase 0 (kk = 0: k-chunks j = quad) ----
  {
    const int pc = (g.quad ^ g.r7) * 8;
#pragma unroll
    for (int i = 0; i < 4; ++i) {
      af[i] = *(const short8*)&ab[(g.wm + i * 16 + g.c) * 64 + pc];
      bf[i] = *(const short8*)&bb[(g.wn + i * 16 + g.c) * 64 + pc];
    }
    if constexpr (ST) {
      stage_a(g, stg, kt2, 0);
      stage_a(g, stg, kt2, 1);
      stage_b(g, stg, kt2, 0);
    }
    __builtin_amdgcn_s_barrier();
    __builtin_amdgcn_s_setprio(1);
#pragma unroll
    for (int mi = 0; mi < 4; ++mi)
#pragma unroll
      for (int ni = 0; ni < 4; ++ni)
        acc[mi][ni] = __builtin_amdgcn_mfma_f32_16x16x32_bf16(
            af[mi], bf[ni], acc[mi][ni], 0, 0, 0);
    __builtin_amdgcn_s_setprio(0);
    __builtin_amdgcn_s_barrier();
  }

  // ---- phase 1 (kk = 1: k-chunks j = 4+quad) ----
  {
    const int pc = ((4 + g.quad) ^ g.r7) * 8;
#pragma unroll
    for (int i = 0; i < 4; ++i) {
      af[i] = *(const short8*)&ab[(g.wm + i * 16 + g.c) * 64 + pc];
      bf[i] = *(const short8*)&bb[(g.wn + i * 16 + g.c) * 64 + pc];
    }
    if constexpr (ST) {
      stage_b(g, stg, kt2, 1);
      stage_b(g, stg, kt2, 2);
      stage_b(g, stg, kt2, 3);
    }
    __builtin_amdgcn_s_barrier();
    __builtin_amdgcn_s_setprio(1);
#pragma unroll
    for (int mi = 0; mi < 4; ++mi)
#pragma unroll
      for (int ni = 0; ni < 4; ++ni)
        acc[mi][ni] = __builtin_amdgcn_mfma_f32_16x16x32_bf16(
            af[mi], bf[ni], acc[mi][ni], 0, 0, 0);
    __builtin_amdgcn_s_setprio(0);
    if constexpr (VM == 6) {
      asm volatile("s_waitcnt vmcnt(6)" ::: "memory");
      __builtin_amdgcn_s_barrier();
    } else if constexpr (VM == 0) {
      asm volatile("s_waitcnt vmcnt(0)" ::: "memory");
      __builtin_amdgcn_s_barrier();
    }
    // VM == -1: last tile, no wait / no trailing barrier
  }
}

__device__ __forceinline__ void gemm_core8(
    const u16* __restrict__ A, const u16* __restrict__ Bt,
    u16* AsB, u16* BsB, int m0, int n0, f32x4 acc[4][4]) {
  const int tid = threadIdx.x;
  const int lane = tid & 63;
  G8 g;
  g.A = A; g.Bt = Bt; g.As = AsB; g.Bs = BsB;
  g.m0 = m0; g.n0 = n0;
  g.wave = tid >> 6;
  g.c = lane & 15; g.quad = lane >> 4; g.r7 = g.c & 7;
  g.wm = (g.wave >> 2) * 64;          // 2 wave-rows
  g.wn = (g.wave & 3) * 64;           // 4 wave-cols
  g.srow = lane >> 3;                 // 0..7 within 8-row DMA group
  g.slc8 = ((lane & 7) ^ g.srow) * 8; // pre-swizzled source column (elems)

  // prologue: stage K-tiles 0 and 1 (6 loads each, per wave)
  stage_a(g, 0, 0, 0); stage_a(g, 0, 0, 1);
  stage_b(g, 0, 0, 0); stage_b(g, 0, 0, 1); stage_b(g, 0, 0, 2); stage_b(g, 0, 0, 3);
  stage_a(g, 1, 1, 0); stage_a(g, 1, 1, 1);
  stage_b(g, 1, 1, 0); stage_b(g, 1, 1, 1); stage_b(g, 1, 1, 2); stage_b(g, 1, 1, 3);
  asm volatile("s_waitcnt vmcnt(6)" ::: "memory");   // tile 0 resident, tile 1 in flight
  __builtin_amdgcn_s_barrier();

  int cur = 0, stg = 2;
#pragma unroll 1
  for (int t = 0; t < 14; ++t) {      // K/64 = 16 tiles; 14 steady-state iters
    tile_step<true, 6>(g, cur, stg, t + 2, acc);
    cur = (cur == 2) ? 0 : cur + 1;
    stg = (stg == 2) ? 0 : stg + 1;
  }
  tile_step<false, 0>(g, cur, 0, 0, acc);   // tile 14 (cur=2): drain tile 15
  tile_step<false, -1>(g, 0, 0, 0, acc);    // tile 15 (cur=0): final
}

// ---------------------------------------------------------------------------
// Split QKV GEMM.  Grid (64 m, 4 n) = 256 blocks.  Z=0: Q (row-major,
// PRE-SCALED by EXPSCALE so attn's exp2 needs no multiply), Z=1: K
// ([b,h,s,d]), Z=2: V ([b,h,d,s]).
// ---------------------------------------------------------------------------
template<int Z>
__global__ __launch_bounds__(512, 2) void gemm_split(
    const u16* __restrict__ A, const u16* __restrict__ Bt,
    const float* __restrict__ bias, u16* __restrict__ Out) {
  __shared__ u16 As[3][AS_T];
  __shared__ u16 Bs[3][BS_T];
  const int m0 = blockIdx.x * 128, n0 = blockIdx.y * 256;

  f32x4 acc[4][4];
#pragma unroll
  for (int i = 0; i < 4; ++i)
#pragma unroll
    for (int j = 0; j < 4; ++j) acc[i][j] = f32x4{0.f, 0.f, 0.f, 0.f};

  gemm_core8(A, Bt, &As[0][0], &Bs[0][0], m0, n0, acc);

  const int lane = threadIdx.x & 63, wave = threadIdx.x >> 6;
  const int wm = (wave >> 2) * 64, wn = (wave & 3) * 64;
  const int c = lane & 15, quad = lane >> 4;
#pragma unroll
  for (int ni = 0; ni < 4; ++ni) {
    int n = n0 + wn + ni * 16 + c;
    float bval = bias[n];
#pragma unroll
    for (int mi = 0; mi < 4; ++mi) {
      int mb = m0 + wm + mi * 16 + quad * 4;
      if constexpr (Z == 2) {
        int bb = mb >> 9, s = mb & 511, hh = n >> 6, d = n & 63;
        ushort4 st;
        __hip_bfloat16 h0 = __float2bfloat16(acc[mi][ni][0] + bval); st.x = *(u16*)&h0;
        __hip_bfloat16 h1 = __float2bfloat16(acc[mi][ni][1] + bval); st.y = *(u16*)&h1;
        __hip_bfloat16 h2 = __float2bfloat16(acc[mi][ni][2] + bval); st.z = *(u16*)&h2;
        __hip_bfloat16 h3 = __float2bfloat16(acc[mi][ni][3] + bval); st.w = *(u16*)&h3;
        *(ushort4*)&Out[(((size_t)(bb * 16 + hh) * 64 + d) << 9) + s] = st;
      } else {
#pragma unroll
        for (int r = 0; r < 4; ++r) {
          int m = mb + r;
          float val = acc[mi][ni][r] + bval;
          if constexpr (Z == 0) val *= EXPSCALE;   // fold softmax scale into Q
          __hip_bfloat16 hb = __float2bfloat16(val);
          if constexpr (Z == 0) {
            Out[(size_t)m * 1024 + n] = *(u16*)&hb;
          } else {
            int bb = m >> 9, s = m & 511, hh = n >> 6, d = n & 63;
            Out[(((size_t)(bb * 16 + hh) * 512 + s) << 6) + d] = *(u16*)&hb;
          }
        }
      }
    }
  }
}

// ---------------------------------------------------------------------------
// Output GEMM: C_f32 = A @ Bt^T + bias.  Grid (64 m, 4 n) = 256 blocks.
// ---------------------------------------------------------------------------
__global__ __launch_bounds__(512, 2) void gemm_out(
    const u16* __restrict__ A, const u16* __restrict__ Bt,
    const float* __restrict__ bias, float* __restrict__ Cf) {
  __shared__ u16 As[3][AS_T];
  __shared__ u16 Bs[3][BS_T];
  const int m0 = blockIdx.x * 128, n0 = blockIdx.y * 256;

  f32x4 acc[4][4];
#pragma unroll
  for (int i = 0; i < 4; ++i)
#pragma unroll
    for (int j = 0; j < 4; ++j) acc[i][j] = f32x4{0.f, 0.f, 0.f, 0.f};

  gemm_core8(A, Bt, &As[0][0], &Bs[0][0], m0, n0, acc);

  const int lane = threadIdx.x & 63, wave = threadIdx.x >> 6;
  const int wm = (wave >> 2) * 64, wn = (wave & 3) * 64;
  const int c = lane & 15, quad = lane >> 4;
#pragma unroll
  for (int ni = 0; ni < 4; ++ni) {
    int n = n0 + wn + ni * 16 + c;
    float bval = bias[n];
#pragma unroll
    for (int mi = 0; mi < 4; ++mi) {
#pragma unroll
      for (int r = 0; r < 4; ++r) {
        int m = m0 + wm + mi * 16 + quad * 4 + r;
        Cf[(size_t)m * 1024 + n] = acc[mi][ni][r] + bval;
      }
    }
  }
}

// ---------------------------------------------------------------------------
// Attention v8: v6 with the softmax VALU chain stripped.
//  - Q pre-scaled by EXPSCALE (in gemm_split<0>) -> p = exp2f(s) directly.
//  - Row-sum l computed by 4 extra MFMAs/tile with an all-ones B fragment:
//    osum[qt] lands in EXACTLY the same accumulator layout as o[qt][dt],
//    deleting the rs VALU chain + epilogue shuffle-reduce/broadcast.
//  - Key-mask hoisted to a wave-uniform full-tile branch (only the last
//    tile of each block is partial).
// Grid (4 qchunks, 16 heads, 16 batches); wave = 32 q rows.
// ---------------------------------------------------------------------------
__global__ __launch_bounds__(256) void attn_v8(
    const u16* __restrict__ Q, const u16* __restrict__ Kt,
    const u16* __restrict__ Vt, const int* __restrict__ lengths,
    u16* __restrict__ O) {
  const int qc = blockIdx.x, h = blockIdx.y, b = blockIdx.z;
  const int t = threadIdx.x;
  const int lane = t & 63, wave = t >> 6;
  const int c = lane & 15, quad = lane >> 4;
  const int kb = quad * 8;
  const int len = lengths[b];
  const int q0 = qc * 128 + wave * 32;

  __shared__ __align__(16) u16 Ks[64 * 64];     // [key][d], swizzled
  __shared__ __align__(16) u16 Vs[64 * 64];     // [d][s],  swizzled
  __shared__ __align__(16) u16 Pt[4][32 * 72];  // per-wave P^T staging

  const size_t bBase = (size_t)b * (S_SZ * D_SZ);
  const size_t hBase = ((size_t)(b * H_SZ + h)) * (S_SZ * DH_SZ);

  short8 aq[2][2];
#pragma unroll
  for (int qt = 0; qt < 2; ++qt) {
    aq[qt][0] = *(const short8*)&Q[bBase + (size_t)(q0 + qt * 16 + c) * 1024 + h * 64 + kb];
    aq[qt][1] = *(const short8*)&Q[bBase + (size_t)(q0 + qt * 16 + c) * 1024 + h * 64 + 32 + kb];
  }

  // all-ones bf16 fragment for the row-sum MFMA
  const short ONE = (short)0x3F80;
  const short8 ones = {ONE, ONE, ONE, ONE, ONE, ONE, ONE, ONE};

  // staging lane geometry: 8 rows x 8 chunks per 64-lane wave-group
  const int srow = lane >> 3;                 // row within 8-row group
  const int slc = (lane & 7) ^ srow;          // swizzled logical chunk

  f32x4 o[2][4];
  f32x4 osum[2];
#pragma unroll
  for (int qt = 0; qt < 2; ++qt) {
    osum[qt] = f32x4{0.f, 0.f, 0.f, 0.f};
#pragma unroll
    for (int i = 0; i < 4; ++i) o[qt][i] = f32x4{0.f, 0.f, 0.f, 0.f};
  }

  const int kmax = (len + 63) & ~63;
  for (int k0 = 0; k0 < kmax; k0 += 64) {
    __syncthreads();   // previous iter's LDS reads complete
#pragma unroll
    for (int g = 0; g < 2; ++g) {
      const int rb = (wave * 2 + g) * 8;      // row base (8 rows per DMA)
      gload_lds16(&Kt[hBase + (size_t)(k0 + rb + srow) * 64 + slc * 8],
                  &Ks[(wave * 2 + g) * 512]);
      gload_lds16(&Vt[hBase + (size_t)(rb + srow) * 512 + k0 + slc * 8],
                  &Vs[(wave * 2 + g) * 512]);
    }
    __syncthreads();   // DMA visible to all waves

    const bool full = (k0 + 64 <= len);       // wave-uniform

    // --- S^T per 16-key sub-tile: rows = keys, cols = q ---
#pragma unroll
    for (int sub = 0; sub < 4; ++sub) {
      const int row = sub * 16 + c;
      short8 bk0 = *(const short8*)&Ks[row * 64 + ((quad ^ (c & 7))) * 8];
      short8 bk1 = *(const short8*)&Ks[row * 64 + (((4 + quad) ^ (c & 7))) * 8];
      const int keyb = k0 + sub * 16 + quad * 4;
#pragma unroll
      for (int qt = 0; qt < 2; ++qt) {
        f32x4 s = {0.f, 0.f, 0.f, 0.f};
        s = __builtin_amdgcn_mfma_f32_16x16x32_bf16(bk0, aq[qt][0], s, 0, 0, 0);
        s = __builtin_amdgcn_mfma_f32_16x16x32_bf16(bk1, aq[qt][1], s, 0, 0, 0);
        float p0, p1, p2, p3;
        if (full) {
          p0 = exp2f(s[0]); p1 = exp2f(s[1]);
          p2 = exp2f(s[2]); p3 = exp2f(s[3]);
        } else {
          p0 = (keyb + 0) < len ? exp2f(s[0]) : 0.f;
          p1 = (keyb + 1) < len ? exp2f(s[1]) : 0.f;
          p2 = (keyb + 2) < len ? exp2f(s[2]) : 0.f;
          p3 = (keyb + 3) < len ? exp2f(s[3]) : 0.f;
        }
        ushort4 st;
        __hip_bfloat16 h0 = __float2bfloat16(p0); st.x = *(u16*)&h0;
        __hip_bfloat16 h1 = __float2bfloat16(p1); st.y = *(u16*)&h1;
        __hip_bfloat16 h2 = __float2bfloat16(p2); st.z = *(u16*)&h2;
        __hip_bfloat16 h3 = __float2bfloat16(p3); st.w = *(u16*)&h3;
        *(ushort4*)&Pt[wave][(qt * 16 + c) * 72 + sub * 16 + quad * 4] = st;
      }
    }
    // --- O += P @ V; l += P @ 1 (V fragments from LDS) ---
#pragma unroll
    for (int ksub = 0; ksub < 2; ++ksub) {
      const short8 pa0 = *(const short8*)&Pt[wave][(c) * 72 + ksub * 32 + kb];
      const short8 pa1 = *(const short8*)&Pt[wave][(16 + c) * 72 + ksub * 32 + kb];
      osum[0] = __builtin_amdgcn_mfma_f32_16x16x32_bf16(pa0, ones, osum[0], 0, 0, 0);
      osum[1] = __builtin_amdgcn_mfma_f32_16x16x32_bf16(pa1, ones, osum[1], 0, 0, 0);
#pragma unroll
      for (int dt = 0; dt < 4; ++dt) {
        const int vrow = dt * 16 + c;
        short8 vb = *(const short8*)&Vs[vrow * 64 + (((ksub * 4 + quad) ^ (c & 7))) * 8];
        o[0][dt] = __builtin_amdgcn_mfma_f32_16x16x32_bf16(pa0, vb, o[0][dt], 0, 0, 0);
        o[1][dt] = __builtin_amdgcn_mfma_f32_16x16x32_bf16(pa1, vb, o[1][dt], 0, 0, 0);
      }
    }
  }

  // --- epilogue: osum[qt][r] is the row-sum for exactly the q-row of
  //     o[qt][dt][r] (same accumulator layout) -> direct divide. ---
#pragma unroll
  for (int qt = 0; qt < 2; ++qt) {
    float inv[4];
#pragma unroll
    for (int r = 0; r < 4; ++r) inv[r] = 1.0f / osum[qt][r];
#pragma unroll
    for (int dt = 0; dt < 4; ++dt) {
#pragma unroll
      for (int r = 0; r < 4; ++r) {
        int s = q0 + qt * 16 + quad * 4 + r;
        float val = o[qt][dt][r] * inv[r];
        __hip_bfloat16 ob = __float2bfloat16(val);
        O[bBase + (size_t)s * 1024 + h * 64 + dt * 16 + c] = *(u16*)&ob;
      }
    }
  }
}

// ---------------------------------------------------------------------------
extern "C" void kernel_launch(void* const* d_in, const int* in_sizes, int n_in,
                              void* d_out, int out_size, void* d_ws, size_t ws_size,
                              hipStream_t stream) {
  const float* v  = (const float*)d_in[0];
  const int* lengths = (const int*)d_in[1];
  const float* Wq = (const float*)d_in[2];
  const float* bq = (const float*)d_in[3];
  const float* Wk = (const float*)d_in[4];
  const float* bk = (const float*)d_in[5];
  const float* Wv = (const float*)d_in[6];
  const float* bv = (const float*)d_in[7];
  const float* Wo = (const float*)d_in[8];
  const float* bo = (const float*)d_in[9];

  char* ws = (char*)d_ws;
  const size_t TSZ = (size_t)M_SZ * D_SZ * 2;   // 16 MiB bf16 activation tensor
  const size_t WSZ = (size_t)1 << 21;           // 2 MiB per transposed weight
  u16* vB  = (u16*)(ws);                        // aliased: AO reuses this after QKV
  u16* AO  = vB;
  u16* WqT = (u16*)(ws + TSZ + 0 * WSZ);
  u16* WkT = (u16*)(ws + TSZ + 1 * WSZ);
  u16* WvT = (u16*)(ws + TSZ + 2 * WSZ);
  u16* WoT = (u16*)(ws + TSZ + 3 * WSZ);
  u16* Qb  = (u16*)(ws + TSZ + 4 * WSZ + 0 * TSZ);
  u16* Kt  = (u16*)(ws + TSZ + 4 * WSZ + 1 * TSZ);
  u16* Vt  = (u16*)(ws + TSZ + 4 * WSZ + 2 * TSZ);

  prep<<<dim3(8192 + 4096), 256, 0, stream>>>(v, vB, Wq, Wk, Wv, Wo, WqT, WkT, WvT, WoT);

  gemm_split<0><<<dim3(64, 4), 512, 0, stream>>>(vB, WqT, bq, Qb);
  gemm_split<1><<<dim3(64, 4), 512, 0, stream>>>(vB, WkT, bk, Kt);
  gemm_split<2><<<dim3(64, 4), 512, 0, stream>>>(vB, WvT, bv, Vt);

  attn_v8<<<dim3(4, 16, 16), 256, 0, stream>>>(Qb, Kt, Vt, lengths, AO);

  gemm_out<<<dim3(64, 4), 512, 0, stream>>>(AO, WoT, bo, (float*)d_out);
}